// Round 7
// baseline (344.358 us; speedup 1.0000x reference)
//
#include <hip/hip_runtime.h>
#include <hip/hip_bf16.h>

// MultiHeadSelfAttention  B=1, S=4096, D=1024, H=16, HD=64. fp32 I/O.
// bf16 MFMA 16x16x32; XOR-swizzled GEMM LDS (conflict-free b128 reads);
// attention: double-buffered K/V DMA (1 barrier/tile), S^T layout so P is
// packed with ds_write_b64, exp2 softmax (Q pre-scaled by log2e/8, exact).

#define S_LEN 4096
#define D_DIM 1024
#define NHEAD 16
#define HDIM  64

typedef __hip_bfloat16 bf16;
typedef __attribute__((ext_vector_type(8))) short bf16x8v;   // 16 B
typedef __attribute__((ext_vector_type(4))) short bf16x4v;   // 8 B
typedef __attribute__((ext_vector_type(4))) float f32x4;

#define MFMA16(a, b, c) __builtin_amdgcn_mfma_f32_16x16x32_bf16((a), (b), (c), 0, 0, 0)
#define LOG2E 1.44269504088896340736f

// Async global->LDS DMA, 16 B/lane (LDS dest = wave-uniform base + lane*16).
__device__ __forceinline__ void async_cp16(const void* g, void* l) {
    __builtin_amdgcn_global_load_lds(
        (const __attribute__((address_space(1))) unsigned int*)g,
        (__attribute__((address_space(3))) unsigned int*)l, 16, 0, 0);
}

__device__ __forceinline__ short bf_bits(float x) {
    union { bf16 h; short s; } u; u.h = __float2bfloat16(x); return u.s;
}

// ---------------------------------------------------------------------------
// fp32 -> bf16 elementwise, 3 tensors via blockIdx.z.
// ---------------------------------------------------------------------------
__global__ __launch_bounds__(256) void cvt_bf16_k(
    const float* __restrict__ x0, const float* __restrict__ x1,
    const float* __restrict__ x2,
    bf16* __restrict__ y0, bf16* __restrict__ y1, bf16* __restrict__ y2)
{
    const float* x = (blockIdx.z == 0) ? x0 : (blockIdx.z == 1) ? x1 : x2;
    bf16*       y = (blockIdx.z == 0) ? y0 : (blockIdx.z == 1) ? y1 : y2;
    const size_t i = ((size_t)blockIdx.x * 256 + threadIdx.x);
    const float4 v = ((const float4*)x)[i];
    union { bf16 h[4]; short4 s; } u;
    u.h[0] = __float2bfloat16(v.x);
    u.h[1] = __float2bfloat16(v.y);
    u.h[2] = __float2bfloat16(v.z);
    u.h[3] = __float2bfloat16(v.w);
    ((short4*)y)[i] = u.s;
}

// ---------------------------------------------------------------------------
// Wt[n][k] = bf16(W[k][n]), 4 matrices via blockIdx.z.
// ---------------------------------------------------------------------------
__global__ __launch_bounds__(256) void transpose_cvt_k(
    const float* __restrict__ W0, const float* __restrict__ W1,
    const float* __restrict__ W2, const float* __restrict__ W3,
    bf16* __restrict__ T0, bf16* __restrict__ T1,
    bf16* __restrict__ T2, bf16* __restrict__ T3)
{
    const float* W = (blockIdx.z == 0) ? W0 : (blockIdx.z == 1) ? W1
                   : (blockIdx.z == 2) ? W2 : W3;
    bf16*       Wt = (blockIdx.z == 0) ? T0 : (blockIdx.z == 1) ? T1
                   : (blockIdx.z == 2) ? T2 : T3;
    __shared__ float t[32][33];
    const int bx = blockIdx.x << 5, by = blockIdx.y << 5;
    const int tx = threadIdx.x & 31, ty = threadIdx.x >> 5;
#pragma unroll
    for (int i = 0; i < 32; i += 8)
        t[ty + i][tx] = W[(size_t)(by + ty + i) * D_DIM + bx + tx];
    __syncthreads();
#pragma unroll
    for (int i = 0; i < 32; i += 8)
        Wt[(size_t)(bx + ty + i) * D_DIM + by + tx] = __float2bfloat16(t[tx][ty + i]);
}

// ---------------------------------------------------------------------------
// GEMM: C(4096x1024) = A @ Wt^T + bias, *scale.  Tile 128x128, BK=64, 4 waves
// 2x2 (64x64 each).  LDS granule XOR-swizzle: slot = row*8 + (kc ^ (row&7))
//   -> DMA stays 128B-coalesced; every b128 frag read spans all 32 banks.
// mode 0: bf16 head-major; mode 2: bf16 [h][hd][row]; mode 1: fp32 row-major.
// ---------------------------------------------------------------------------
struct GemmJob {
    const bf16* A; const bf16* Wt; const float* bias; void* out;
    int mode; float scale;
};

__global__ __launch_bounds__(256) void gemm_k(GemmJob j0, GemmJob j1, GemmJob j2)
{
    const GemmJob j = (blockIdx.z == 0) ? j0 : (blockIdx.z == 1) ? j1 : j2;
    const int K = D_DIM;
    const int bn = blockIdx.x << 7;
    const int bm = blockIdx.y << 7;
    const int tid = threadIdx.x;
    const int w = tid >> 6, lane = tid & 63;
    const int col = lane & 15, g = lane >> 4;
    const int wr = (w >> 1) << 6, wc = (w & 1) << 6;

    __shared__ bf16 As[128 * 64];   // 16 KB, swizzled granules
    __shared__ bf16 Bs[128 * 64];

    f32x4 acc[4][4];
#pragma unroll
    for (int i = 0; i < 4; ++i)
#pragma unroll
        for (int jj = 0; jj < 4; ++jj) acc[i][jj] = (f32x4){0.f, 0.f, 0.f, 0.f};

    for (int kb = 0; kb < K; kb += 64) {
        __syncthreads();
#pragma unroll
        for (int e = 0; e < 4; ++e) {
            const int lin = (e << 8) + tid;          // swizzled slot id 0..1023
            const int row = lin >> 3, kcs = lin & 7;
            const int kcg = kcs ^ (row & 7);         // global k-chunk fetched
            async_cp16(j.A  + (size_t)(bm + row) * K + kb + (kcg << 3), &As[lin << 3]);
            async_cp16(j.Wt + (size_t)(bn + row) * K + kb + (kcg << 3), &Bs[lin << 3]);
        }
        __syncthreads();

#pragma unroll
        for (int s = 0; s < 2; ++s) {
            bf16x8v af[4], bfv[4];
#pragma unroll
            for (int i = 0; i < 4; ++i) {
                const int row = wr + (i << 4) + col;
                af[i] = *(const bf16x8v*)&As[(((row << 3) + (((s << 2) + g) ^ (row & 7)))) << 3];
            }
#pragma unroll
            for (int jj = 0; jj < 4; ++jj) {
                const int row = wc + (jj << 4) + col;
                bfv[jj] = *(const bf16x8v*)&Bs[(((row << 3) + (((s << 2) + g) ^ (row & 7)))) << 3];
            }
#pragma unroll
            for (int i = 0; i < 4; ++i)
#pragma unroll
                for (int jj = 0; jj < 4; ++jj)
                    acc[i][jj] = MFMA16(af[i], bfv[jj], acc[i][jj]);
        }
    }

#pragma unroll
    for (int i = 0; i < 4; ++i)
#pragma unroll
    for (int jj = 0; jj < 4; ++jj)
#pragma unroll
    for (int reg = 0; reg < 4; ++reg) {
        const int row = bm + wr + (i << 4) + (g << 2) + reg;  // C/D: row=(lane>>4)*4+reg
        const int cg  = bn + wc + (jj << 4) + col;            // C/D: col=lane&15
        const float vv = (acc[i][jj][reg] + j.bias[cg]) * j.scale;
        if (j.mode == 0)
            ((bf16*)j.out)[(((size_t)(cg >> 6)) * S_LEN + row) * HDIM + (cg & 63)] =
                __float2bfloat16(vv);
        else if (j.mode == 2)
            ((bf16*)j.out)[((size_t)(cg >> 6) * HDIM + (cg & 63)) * S_LEN + row] =
                __float2bfloat16(vv);
        else
            ((float*)j.out)[(size_t)row * D_DIM + cg] = vv;
    }
}

// ---------------------------------------------------------------------------
// Flash attention. Block = 64 q-rows (4 waves x 16), causal, heavy-first.
// Qp pre-scaled by log2e/8 -> p = exp2(s) exactly (|s| small, no shift needed).
// Double-buffered K/V: DMA tile kb+1 issued before computing kb; ONE barrier
// per tile, so the vmcnt drain at the barrier overlaps a full compute phase.
// S^T trick: QK^T computed as MFMA(K, Q) so each lane owns 4 consecutive keys
// for one q -> P written as packed ds_write_b64 into plain frag-major slab
// (bank math: 32 banks x 4 words, uniform -> conflict-free).
// ---------------------------------------------------------------------------
__global__ __launch_bounds__(256) void attn_mfma_k(
    const bf16* __restrict__ Qp, const bf16* __restrict__ Kp,
    const bf16* __restrict__ Vt, bf16* __restrict__ ctx)
{
    __shared__ bf16 Ks[2][4096];     // 16 KB  frag-major [t][G][c][8]
    __shared__ bf16 Vs[2][4096];     // 16 KB
    __shared__ bf16 Ps[4][1024];     //  8 KB  per-wave frag-major [Gk][m][8]

    const int bid = blockIdx.x;
    const int qb  = 63 - (bid >> 4);   // heavy-first
    const int h   = bid & 15;
    const int q0  = qb << 6;
    const int tid = threadIdx.x, w = tid >> 6, lane = tid & 63;
    const int col = lane & 15, g = lane >> 4;

    const bf16* Kh = Kp + (size_t)h * S_LEN * HDIM;
    const bf16* Vh = Vt + (size_t)h * HDIM * S_LEN;

    // Q as B-operand: n = q-within-16 = col, k = g*8+j (+32 for step 1)
    const size_t qrow_base = ((size_t)h * S_LEN + q0 + (w << 4) + col) * HDIM + (g << 3);
    const bf16x8v qf0 = *(const bf16x8v*)(Qp + qrow_base);
    const bf16x8v qf1 = *(const bf16x8v*)(Qp + qrow_base + 32);

    float pl = 0.f;                   // per-lane l partial (q = col)
    f32x4 acco[4];
#pragma unroll
    for (int t = 0; t < 4; ++t) acco[t] = (f32x4){0.f, 0.f, 0.f, 0.f};

    const int nkb = qb + 1;

    // prologue: DMA tile 0 -> buffer 0
#pragma unroll
    for (int e = 0; e < 2; ++e) {
        const int lin = (e << 8) + tid;
        const int t = lin >> 7, G = (lin >> 4) & 7, c = lin & 15;
        async_cp16(Kh + (size_t)((t << 4) + c) * HDIM + (G << 3), &Ks[0][lin << 3]);
        async_cp16(Vh + (size_t)((t << 4) + c) * S_LEN + (G << 3), &Vs[0][lin << 3]);
    }

    for (int kb = 0; kb < nkb; ++kb) {
        const int kk0 = kb << 6;
        // drains DMA for tile kb; all waves done reading buf[(kb+1)&1] (tile kb-1)
        __syncthreads();
        if (kb + 1 < nkb) {
            const int nk0 = (kb + 1) << 6;
            const int nb  = (kb + 1) & 1;
#pragma unroll
            for (int e = 0; e < 2; ++e) {
                const int lin = (e << 8) + tid;
                const int t = lin >> 7, G = (lin >> 4) & 7, c = lin & 15;
                async_cp16(Kh + (size_t)(nk0 + (t << 4) + c) * HDIM + (G << 3),
                           &Ks[nb][lin << 3]);
                async_cp16(Vh + (size_t)((t << 4) + c) * S_LEN + nk0 + (G << 3),
                           &Vs[nb][lin << 3]);
            }
        }
        const bf16* K0 = Ks[kb & 1];
        const bf16* V0 = Vs[kb & 1];

        // S^T = (Q K^T)^T : A = K (m=key), B = Q (n=q)
        f32x4 sa[4];
#pragma unroll
        for (int t = 0; t < 4; ++t) sa[t] = (f32x4){0.f, 0.f, 0.f, 0.f};
#pragma unroll
        for (int t = 0; t < 4; ++t) {
            const bf16x8v kf0 = *(const bf16x8v*)&K0[((t << 7) + (g << 4) + col) << 3];
            const bf16x8v kf1 = *(const bf16x8v*)&K0[((t << 7) + 64 + (g << 4) + col) << 3];
            sa[t] = MFMA16(kf0, qf0, sa[t]);
            sa[t] = MFMA16(kf1, qf1, sa[t]);
        }

        // lane holds S^T[key = kk0+t*16+g*4+reg][q = q0+w*16+col]
        const bool lastt = (kb == nkb - 1);
        const int qq = (w << 4) + col;           // q offset within block
#pragma unroll
        for (int t = 0; t < 4; ++t) {
            float p[4];
#pragma unroll
            for (int reg = 0; reg < 4; ++reg) {
                const int krel = (t << 4) + (g << 2) + reg;
                p[reg] = (lastt && krel > qq) ? 0.f
                       : __builtin_amdgcn_exp2f(sa[t][reg]);
            }
            pl += (p[0] + p[1]) + (p[2] + p[3]);
            // packed write: keys t*16+g*4+{0..3} -> granule Gk=2t+(g>>1), j0=(g&1)*4
            bf16x4v pv = { bf_bits(p[0]), bf_bits(p[1]), bf_bits(p[2]), bf_bits(p[3]) };
            const int off = (((((t << 1) + (g >> 1)) << 4) + col) << 3) + ((g & 1) << 2);
            *(bf16x4v*)&Ps[w][off] = pv;
        }

        // O += P V : A = P (m=q), B = V (n=dim)
        const bf16x8v pf0 = *(const bf16x8v*)&Ps[w][((g << 4) + col) << 3];
        const bf16x8v pf1 = *(const bf16x8v*)&Ps[w][(((4 + g) << 4) + col) << 3];
#pragma unroll
        for (int t = 0; t < 4; ++t) {
            const bf16x8v vf0 = *(const bf16x8v*)&V0[((t << 7) + (g << 4) + col) << 3];
            const bf16x8v vf1 = *(const bf16x8v*)&V0[((t << 7) + 64 + (g << 4) + col) << 3];
            acco[t] = MFMA16(pf0, vf0, acco[t]);
            acco[t] = MFMA16(pf1, vf1, acco[t]);
        }
    }

    // l(q=col): reduce pl over the 4 g-lanes, then permute to q=g*4+reg
    float l = pl;
    l += __shfl_xor(l, 16);
    l += __shfl_xor(l, 32);
    float lr[4];
#pragma unroll
    for (int reg = 0; reg < 4; ++reg) lr[reg] = __shfl(l, (g << 2) + reg);

#pragma unroll
    for (int t = 0; t < 4; ++t)
#pragma unroll
        for (int reg = 0; reg < 4; ++reg) {
            const int row = q0 + (w << 4) + (g << 2) + reg;
            ctx[(size_t)row * D_DIM + h * HDIM + (t << 4) + col] =
                __float2bfloat16(acco[t][reg] / lr[reg]);
        }
}

// ---------------------------------------------------------------------------
extern "C" void kernel_launch(void* const* d_in, const int* in_sizes, int n_in,
                              void* d_out, int out_size, void* d_ws, size_t ws_size,
                              hipStream_t stream)
{
    const float* q  = (const float*)d_in[0];
    const float* k  = (const float*)d_in[1];
    const float* v  = (const float*)d_in[2];
    // d_in[3] = causal mask, implemented analytically
    const float* Wq = (const float*)d_in[4];
    const float* bq = (const float*)d_in[5];
    const float* Wk = (const float*)d_in[6];
    const float* bk = (const float*)d_in[7];
    const float* Wv = (const float*)d_in[8];
    const float* bv = (const float*)d_in[9];
    const float* Wo = (const float*)d_in[10];
    const float* bo = (const float*)d_in[11];

    const size_t PE  = (size_t)S_LEN * D_DIM;
    const size_t WTE = (size_t)D_DIM * D_DIM;
    const float qscale = 0.125f * LOG2E;   // fold 1/sqrt(64) and log2(e) into Qp

    const dim3 tg(32, 32, 4);
    const dim3 gg(D_DIM / 128, S_LEN / 128, 1);
    const dim3 gg3(D_DIM / 128, S_LEN / 128, 3);
    const dim3 cg((unsigned)(PE / 1024), 1, 3);

    if (ws_size >= (size_t)64 * 1024 * 1024) {
        // ---- fused-QKV path (56 MB) ----
        bf16* Qb = (bf16*)d_ws;
        bf16* Kb = Qb + PE;
        bf16* Vb = Kb + PE;
        bf16* Qp = Vb + PE;
        bf16* Kp = Qp + PE;
        bf16* Vt = Kp + PE;
        bf16* Wtq = Vt + PE;
        bf16* Wtk = Wtq + WTE;
        bf16* Wtv = Wtk + WTE;
        bf16* Wto = Wtv + WTE;
        bf16* ctx = Qb;

        transpose_cvt_k<<<tg, 256, 0, stream>>>(Wq, Wk, Wv, Wo, Wtq, Wtk, Wtv, Wto);
        cvt_bf16_k<<<cg, 256, 0, stream>>>(q, k, v, Qb, Kb, Vb);

        GemmJob jq{Qb, Wtq, bq, Qp, 0, qscale};
        GemmJob jk{Kb, Wtk, bk, Kp, 0, 1.0f};
        GemmJob jv{Vb, Wtv, bv, Vt, 2, 1.0f};
        gemm_k<<<gg3, 256, 0, stream>>>(jq, jk, jv);

        attn_mfma_k<<<dim3(1024), 256, 0, stream>>>(Qp, Kp, Vt, ctx);

        GemmJob jo{ctx, Wto, bo, d_out, 1, 1.0f};
        gemm_k<<<gg, 256, 0, stream>>>(jo, jo, jo);
    } else {
        // ---- sequential path (40 MB) ----
        bf16* X  = (bf16*)d_ws;
        bf16* Qp = X + PE;
        bf16* Kp = Qp + PE;
        bf16* Vt = Kp + PE;
        bf16* Wtq = Vt + PE;
        bf16* Wtk = Wtq + WTE;
        bf16* Wtv = Wtk + WTE;
        bf16* Wto = Wtv + WTE;

        transpose_cvt_k<<<tg, 256, 0, stream>>>(Wq, Wk, Wv, Wo, Wtq, Wtk, Wtv, Wto);

        const dim3 cg1((unsigned)(PE / 1024), 1, 1);
        cvt_bf16_k<<<cg1, 256, 0, stream>>>(q, q, q, X, X, X);
        GemmJob jq{X, Wtq, bq, Qp, 0, qscale};
        gemm_k<<<gg, 256, 0, stream>>>(jq, jq, jq);
        cvt_bf16_k<<<cg1, 256, 0, stream>>>(k, k, k, X, X, X);
        GemmJob jk{X, Wtk, bk, Kp, 0, 1.0f};
        gemm_k<<<gg, 256, 0, stream>>>(jk, jk, jk);
        cvt_bf16_k<<<cg1, 256, 0, stream>>>(v, v, v, X, X, X);
        GemmJob jv{X, Wtv, bv, Vt, 2, 1.0f};
        gemm_k<<<gg, 256, 0, stream>>>(jv, jv, jv);

        attn_mfma_k<<<dim3(1024), 256, 0, stream>>>(Qp, Kp, Vt, X);

        GemmJob jo{X, Wto, bo, d_out, 1, 1.0f};
        gemm_k<<<gg, 256, 0, stream>>>(jo, jo, jo);
    }
}

// Round 8
// 337.931 us; speedup vs baseline: 1.0190x; 1.0190x over previous
//
#include <hip/hip_runtime.h>
#include <hip/hip_bf16.h>

// MultiHeadSelfAttention  B=1, S=4096, D=1024, H=16, HD=64. fp32 I/O.
// bf16 MFMA 16x16x32. Attention: PAIRED blocks (q-tiles p and 63-p) -> every
// block does exactly 65 tile-works (zero tail), K/V LDS tiles and fragment
// reads shared between the two q-groups. XOR-swizzled P slab (conflict-free
// b64 writes + b128 reads). GEMM: 128x64 tile + XOR k-chunk swizzle.

#define S_LEN 4096
#define D_DIM 1024
#define NHEAD 16
#define HDIM  64

typedef __hip_bfloat16 bf16;
typedef __attribute__((ext_vector_type(8))) short bf16x8v;   // 16 B
typedef __attribute__((ext_vector_type(4))) short bf16x4v;   // 8 B
typedef __attribute__((ext_vector_type(4))) float f32x4;

#define MFMA16(a, b, c) __builtin_amdgcn_mfma_f32_16x16x32_bf16((a), (b), (c), 0, 0, 0)
#define LOG2E 1.44269504088896340736f

__device__ __forceinline__ void async_cp16(const void* g, void* l) {
    __builtin_amdgcn_global_load_lds(
        (const __attribute__((address_space(1))) unsigned int*)g,
        (__attribute__((address_space(3))) unsigned int*)l, 16, 0, 0);
}

__device__ __forceinline__ short bf_bits(float x) {
    union { bf16 h; short s; } u; u.h = __float2bfloat16(x); return u.s;
}

// ---------------------------------------------------------------------------
// fp32 -> bf16 elementwise, 3 tensors via blockIdx.z.
// ---------------------------------------------------------------------------
__global__ __launch_bounds__(256) void cvt_bf16_k(
    const float* __restrict__ x0, const float* __restrict__ x1,
    const float* __restrict__ x2,
    bf16* __restrict__ y0, bf16* __restrict__ y1, bf16* __restrict__ y2)
{
    const float* x = (blockIdx.z == 0) ? x0 : (blockIdx.z == 1) ? x1 : x2;
    bf16*       y = (blockIdx.z == 0) ? y0 : (blockIdx.z == 1) ? y1 : y2;
    const size_t i = ((size_t)blockIdx.x * 256 + threadIdx.x);
    const float4 v = ((const float4*)x)[i];
    union { bf16 h[4]; short4 s; } u;
    u.h[0] = __float2bfloat16(v.x);
    u.h[1] = __float2bfloat16(v.y);
    u.h[2] = __float2bfloat16(v.z);
    u.h[3] = __float2bfloat16(v.w);
    ((short4*)y)[i] = u.s;
}

// ---------------------------------------------------------------------------
// Wt[n][k] = bf16(W[k][n]), 4 matrices via blockIdx.z.
// ---------------------------------------------------------------------------
__global__ __launch_bounds__(256) void transpose_cvt_k(
    const float* __restrict__ W0, const float* __restrict__ W1,
    const float* __restrict__ W2, const float* __restrict__ W3,
    bf16* __restrict__ T0, bf16* __restrict__ T1,
    bf16* __restrict__ T2, bf16* __restrict__ T3)
{
    const float* W = (blockIdx.z == 0) ? W0 : (blockIdx.z == 1) ? W1
                   : (blockIdx.z == 2) ? W2 : W3;
    bf16*       Wt = (blockIdx.z == 0) ? T0 : (blockIdx.z == 1) ? T1
                   : (blockIdx.z == 2) ? T2 : T3;
    __shared__ float t[32][33];
    const int bx = blockIdx.x << 5, by = blockIdx.y << 5;
    const int tx = threadIdx.x & 31, ty = threadIdx.x >> 5;
#pragma unroll
    for (int i = 0; i < 32; i += 8)
        t[ty + i][tx] = W[(size_t)(by + ty + i) * D_DIM + bx + tx];
    __syncthreads();
#pragma unroll
    for (int i = 0; i < 32; i += 8)
        Wt[(size_t)(bx + ty + i) * D_DIM + by + tx] = __float2bfloat16(t[tx][ty + i]);
}

// ---------------------------------------------------------------------------
// GEMM: C(4096x1024) = A @ Wt^T + bias, *scale.  Tile 128x64, BK=64, 4 waves
// 2x2 (64 rows x 32 cols each).  XOR k-chunk swizzle: slot kc = kcg ^ (row&7)
//   -> frag reads spread over all 32 banks (R6 layout used banks 0-15 only).
// mode 0: bf16 head-major; mode 2: bf16 [h][hd][row]; mode 1: fp32 row-major.
// ---------------------------------------------------------------------------
struct GemmJob {
    const bf16* A; const bf16* Wt; const float* bias; void* out;
    int mode; float scale;
};

__global__ __launch_bounds__(256) void gemm_k(GemmJob j0, GemmJob j1, GemmJob j2)
{
    const GemmJob j = (blockIdx.z == 0) ? j0 : (blockIdx.z == 1) ? j1 : j2;
    const int K = D_DIM;
    const int bn = blockIdx.x << 6;
    const int bm = blockIdx.y << 7;
    const int tid = threadIdx.x;
    const int w = tid >> 6, lane = tid & 63;
    const int col = lane & 15, g = lane >> 4;
    const int wr = (w >> 1) << 6, wc = (w & 1) << 5;

    __shared__ bf16 As[128 * 64];   // 16 KB, swizzled k-chunks
    __shared__ bf16 Bs[64 * 64];    //  8 KB

    f32x4 acc[4][2];
#pragma unroll
    for (int i = 0; i < 4; ++i)
#pragma unroll
        for (int jj = 0; jj < 2; ++jj) acc[i][jj] = (f32x4){0.f, 0.f, 0.f, 0.f};

    for (int kb = 0; kb < K; kb += 64) {
        __syncthreads();
#pragma unroll
        for (int e = 0; e < 4; ++e) {
            const int lin = (e << 8) + tid;          // slot 0..1023
            const int row = lin >> 3, kcs = lin & 7;
            const int kcg = kcs ^ (row & 7);
            async_cp16(j.A + (size_t)(bm + row) * K + kb + (kcg << 3), &As[lin << 3]);
        }
#pragma unroll
        for (int e = 0; e < 2; ++e) {
            const int lin = (e << 8) + tid;          // slot 0..511
            const int row = lin >> 3, kcs = lin & 7;
            const int kcg = kcs ^ (row & 7);
            async_cp16(j.Wt + (size_t)(bn + row) * K + kb + (kcg << 3), &Bs[lin << 3]);
        }
        __syncthreads();

#pragma unroll
        for (int s = 0; s < 2; ++s) {
            bf16x8v af[4], bfv[2];
#pragma unroll
            for (int i = 0; i < 4; ++i) {
                const int row = wr + (i << 4) + col;
                af[i] = *(const bf16x8v*)&As[((row << 3) + (((s << 2) + g) ^ (row & 7))) << 3];
            }
#pragma unroll
            for (int jj = 0; jj < 2; ++jj) {
                const int row = wc + (jj << 4) + col;
                bfv[jj] = *(const bf16x8v*)&Bs[((row << 3) + (((s << 2) + g) ^ (row & 7))) << 3];
            }
#pragma unroll
            for (int i = 0; i < 4; ++i)
#pragma unroll
                for (int jj = 0; jj < 2; ++jj)
                    acc[i][jj] = MFMA16(af[i], bfv[jj], acc[i][jj]);
        }
    }

#pragma unroll
    for (int i = 0; i < 4; ++i)
#pragma unroll
    for (int jj = 0; jj < 2; ++jj)
#pragma unroll
    for (int reg = 0; reg < 4; ++reg) {
        const int row = bm + wr + (i << 4) + (g << 2) + reg;  // C/D: row=(lane>>4)*4+reg
        const int cg  = bn + wc + (jj << 4) + col;            // C/D: col=lane&15
        const float vv = (acc[i][jj][reg] + j.bias[cg]) * j.scale;
        if (j.mode == 0)
            ((bf16*)j.out)[(((size_t)(cg >> 6)) * S_LEN + row) * HDIM + (cg & 63)] =
                __float2bfloat16(vv);
        else if (j.mode == 2)
            ((bf16*)j.out)[((size_t)(cg >> 6) * HDIM + (cg & 63)) * S_LEN + row] =
                __float2bfloat16(vv);
        else
            ((float*)j.out)[(size_t)row * D_DIM + cg] = vv;
    }
}

// ---------------------------------------------------------------------------
// Flash attention, PAIRED blocks. Block (pr,h) handles q-tiles A=pr, B=63-pr:
// per-block work = (pr+1)+(64-pr) = 65 tile-works, uniform across all 512
// blocks (2/CU, zero tail). K/V tile + kf/vf fragment reads are shared by
// both q-groups. Zero-shift exp2 softmax (Qp pre-scaled by log2e/8, exact).
// Double-buffered K/V DMA, 1 barrier/tile.
// P slab swizzle: entry (q=m, key=Gk*8+j) at [(Gk*16 + (m ^ ((Gk&3)<<2)))*8+j]
//   writes (b64, fixed t): bank = (m'*4 + (g&1)*2)%32, both g>>1 subcases
//   bijective in m' -> uniform 4 accesses/bank = conflict-free; reads (b128):
//   8 accesses/bank uniform = conflict-free.
// ---------------------------------------------------------------------------
__global__ __launch_bounds__(256) void attn_mfma_k(
    const bf16* __restrict__ Qp, const bf16* __restrict__ Kp,
    const bf16* __restrict__ Vt, bf16* __restrict__ ctx)
{
    __shared__ bf16 Ks[2][4096];     // 16 KB  frag-major [t][G][c][8]
    __shared__ bf16 Vs[2][4096];     // 16 KB
    __shared__ bf16 PsA[4][1024];    //  8 KB  per-wave swizzled slabs
    __shared__ bf16 PsB[4][1024];    //  8 KB

    const int bid = blockIdx.x;
    const int pr  = bid >> 4;          // pair 0..31
    const int h   = bid & 15;
    const int qbA = pr, qbB = 63 - pr;
    const int qA0 = qbA << 6, qB0 = qbB << 6;
    const int nkbA = qbA + 1, nkbB = qbB + 1;
    const int tid = threadIdx.x, w = tid >> 6, lane = tid & 63;
    const int col = lane & 15, g = lane >> 4;

    const bf16* Kh = Kp + (size_t)h * S_LEN * HDIM;
    const bf16* Vh = Vt + (size_t)h * HDIM * S_LEN;

    // Q as B-operand (n = q = col, k = g*8+j; +32 for kstep 1)
    const size_t qbaseA = ((size_t)h * S_LEN + qA0 + (w << 4) + col) * HDIM + (g << 3);
    const bf16x8v qfA0 = *(const bf16x8v*)(Qp + qbaseA);
    const bf16x8v qfA1 = *(const bf16x8v*)(Qp + qbaseA + 32);
    const size_t qbaseB = ((size_t)h * S_LEN + qB0 + (w << 4) + col) * HDIM + (g << 3);
    const bf16x8v qfB0 = *(const bf16x8v*)(Qp + qbaseB);
    const bf16x8v qfB1 = *(const bf16x8v*)(Qp + qbaseB + 32);

    // P slab offsets (elems), kb-invariant
    int pwoff[4];
#pragma unroll
    for (int t = 0; t < 4; ++t) {
        const int Gk = (t << 1) + (g >> 1);
        pwoff[t] = (((Gk << 4) + (col ^ ((Gk & 3) << 2))) << 3) + ((g & 1) << 2);
    }
    const int proff0 = (((g) << 4) + (col ^ ((g & 3) << 2))) << 3;       // Gk=g
    const int proff1 = (((4 + g) << 4) + (col ^ ((g & 3) << 2))) << 3;   // Gk=4+g, (4+g)&3=g

    float plA = 0.f, plB = 0.f;
    f32x4 accoA[4], accoB[4];
#pragma unroll
    for (int t = 0; t < 4; ++t) {
        accoA[t] = (f32x4){0.f, 0.f, 0.f, 0.f};
        accoB[t] = (f32x4){0.f, 0.f, 0.f, 0.f};
    }
    const int qq = (w << 4) + col;     // q offset within a 64-row group

    // prologue: DMA tile 0 -> buffer 0
#pragma unroll
    for (int e = 0; e < 2; ++e) {
        const int lin = (e << 8) + tid;
        const int t = lin >> 7, G = (lin >> 4) & 7, c = lin & 15;
        async_cp16(Kh + (size_t)((t << 4) + c) * HDIM + (G << 3), &Ks[0][lin << 3]);
        async_cp16(Vh + (size_t)((t << 4) + c) * S_LEN + (G << 3), &Vs[0][lin << 3]);
    }

    for (int kb = 0; kb < nkbB; ++kb) {
        __syncthreads();   // drains DMA(kb); all waves done reading buf[(kb+1)&1]
        if (kb + 1 < nkbB) {
            const int nk0 = (kb + 1) << 6;
            const int nb  = (kb + 1) & 1;
#pragma unroll
            for (int e = 0; e < 2; ++e) {
                const int lin = (e << 8) + tid;
                const int t = lin >> 7, G = (lin >> 4) & 7, c = lin & 15;
                async_cp16(Kh + (size_t)(nk0 + (t << 4) + c) * HDIM + (G << 3),
                           &Ks[nb][lin << 3]);
                async_cp16(Vh + (size_t)((t << 4) + c) * S_LEN + nk0 + (G << 3),
                           &Vs[nb][lin << 3]);
            }
        }
        const bf16* K0 = Ks[kb & 1];
        const bf16* V0 = Vs[kb & 1];
        const bool doA = (kb < nkbA);

        // S^T = MFMA(K, Q): kf shared between groups
        f32x4 saA[4], saB[4];
#pragma unroll
        for (int t = 0; t < 4; ++t) {
            saA[t] = (f32x4){0.f, 0.f, 0.f, 0.f};
            saB[t] = (f32x4){0.f, 0.f, 0.f, 0.f};
        }
#pragma unroll
        for (int t = 0; t < 4; ++t) {
            const bf16x8v kf0 = *(const bf16x8v*)&K0[((t << 7) + (g << 4) + col) << 3];
            const bf16x8v kf1 = *(const bf16x8v*)&K0[((t << 7) + 64 + (g << 4) + col) << 3];
            saB[t] = MFMA16(kf0, qfB0, saB[t]);
            saB[t] = MFMA16(kf1, qfB1, saB[t]);
            if (doA) {
                saA[t] = MFMA16(kf0, qfA0, saA[t]);
                saA[t] = MFMA16(kf1, qfA1, saA[t]);
            }
        }

        // softmax + P for group B (lane holds S^T[key=t*16+g*4+reg][q=col])
        const bool lastB = (kb == nkbB - 1);
#pragma unroll
        for (int t = 0; t < 4; ++t) {
            float p[4];
#pragma unroll
            for (int reg = 0; reg < 4; ++reg) {
                const int krel = (t << 4) + (g << 2) + reg;
                p[reg] = (lastB && krel > qq) ? 0.f
                       : __builtin_amdgcn_exp2f(saB[t][reg]);
            }
            plB += (p[0] + p[1]) + (p[2] + p[3]);
            bf16x4v pv = { bf_bits(p[0]), bf_bits(p[1]), bf_bits(p[2]), bf_bits(p[3]) };
            *(bf16x4v*)&PsB[w][pwoff[t]] = pv;
        }
        if (doA) {
            const bool lastA = (kb == nkbA - 1);
#pragma unroll
            for (int t = 0; t < 4; ++t) {
                float p[4];
#pragma unroll
                for (int reg = 0; reg < 4; ++reg) {
                    const int krel = (t << 4) + (g << 2) + reg;
                    p[reg] = (lastA && krel > qq) ? 0.f
                           : __builtin_amdgcn_exp2f(saA[t][reg]);
                }
                plA += (p[0] + p[1]) + (p[2] + p[3]);
                bf16x4v pv = { bf_bits(p[0]), bf_bits(p[1]), bf_bits(p[2]), bf_bits(p[3]) };
                *(bf16x4v*)&PsA[w][pwoff[t]] = pv;
            }
        }

        // O += P V : vf shared between groups
        const bf16x8v pfB0 = *(const bf16x8v*)&PsB[w][proff0];
        const bf16x8v pfB1 = *(const bf16x8v*)&PsB[w][proff1];
        bf16x8v pfA0, pfA1;
        if (doA) {
            pfA0 = *(const bf16x8v*)&PsA[w][proff0];
            pfA1 = *(const bf16x8v*)&PsA[w][proff1];
        }
#pragma unroll
        for (int t = 0; t < 4; ++t) {
            const bf16x8v vf0 = *(const bf16x8v*)&V0[((t << 7) + (g << 4) + col) << 3];
            const bf16x8v vf1 = *(const bf16x8v*)&V0[((t << 7) + 64 + (g << 4) + col) << 3];
            accoB[t] = MFMA16(pfB0, vf0, accoB[t]);
            accoB[t] = MFMA16(pfB1, vf1, accoB[t]);
            if (doA) {
                accoA[t] = MFMA16(pfA0, vf0, accoA[t]);
                accoA[t] = MFMA16(pfA1, vf1, accoA[t]);
            }
        }
    }

    // l(q=col): reduce over lane bits 4-5, then permute to q=g*4+reg
    float lA = plA, lB = plB;
    lA += __shfl_xor(lA, 16); lA += __shfl_xor(lA, 32);
    lB += __shfl_xor(lB, 16); lB += __shfl_xor(lB, 32);
#pragma unroll
    for (int reg = 0; reg < 4; ++reg) {
        const float lrA = __shfl(lA, (g << 2) + reg);
        const float lrB = __shfl(lB, (g << 2) + reg);
#pragma unroll
        for (int t = 0; t < 4; ++t) {
            const int rowA = qA0 + (w << 4) + (g << 2) + reg;
            const int rowB = qB0 + (w << 4) + (g << 2) + reg;
            ctx[(size_t)rowA * D_DIM + h * HDIM + (t << 4) + col] =
                __float2bfloat16(accoA[t][reg] / lrA);
            ctx[(size_t)rowB * D_DIM + h * HDIM + (t << 4) + col] =
                __float2bfloat16(accoB[t][reg] / lrB);
        }
    }
}

// ---------------------------------------------------------------------------
extern "C" void kernel_launch(void* const* d_in, const int* in_sizes, int n_in,
                              void* d_out, int out_size, void* d_ws, size_t ws_size,
                              hipStream_t stream)
{
    const float* q  = (const float*)d_in[0];
    const float* k  = (const float*)d_in[1];
    const float* v  = (const float*)d_in[2];
    // d_in[3] = causal mask, implemented analytically
    const float* Wq = (const float*)d_in[4];
    const float* bq = (const float*)d_in[5];
    const float* Wk = (const float*)d_in[6];
    const float* bk = (const float*)d_in[7];
    const float* Wv = (const float*)d_in[8];
    const float* bv = (const float*)d_in[9];
    const float* Wo = (const float*)d_in[10];
    const float* bo = (const float*)d_in[11];

    const size_t PE  = (size_t)S_LEN * D_DIM;
    const size_t WTE = (size_t)D_DIM * D_DIM;
    const float qscale = 0.125f * LOG2E;   // fold 1/sqrt(64) + log2(e) into Qp

    const dim3 tg(32, 32, 4);
    const dim3 gg(D_DIM / 64, S_LEN / 128, 1);
    const dim3 gg3(D_DIM / 64, S_LEN / 128, 3);
    const dim3 cg((unsigned)(PE / 1024), 1, 3);

    if (ws_size >= (size_t)64 * 1024 * 1024) {
        // ---- fused-QKV path (56 MB) ----
        bf16* Qb = (bf16*)d_ws;
        bf16* Kb = Qb + PE;
        bf16* Vb = Kb + PE;
        bf16* Qp = Vb + PE;
        bf16* Kp = Qp + PE;
        bf16* Vt = Kp + PE;
        bf16* Wtq = Vt + PE;
        bf16* Wtk = Wtq + WTE;
        bf16* Wtv = Wtk + WTE;
        bf16* Wto = Wtv + WTE;
        bf16* ctx = Qb;

        transpose_cvt_k<<<tg, 256, 0, stream>>>(Wq, Wk, Wv, Wo, Wtq, Wtk, Wtv, Wto);
        cvt_bf16_k<<<cg, 256, 0, stream>>>(q, k, v, Qb, Kb, Vb);

        GemmJob jq{Qb, Wtq, bq, Qp, 0, qscale};
        GemmJob jk{Kb, Wtk, bk, Kp, 0, 1.0f};
        GemmJob jv{Vb, Wtv, bv, Vt, 2, 1.0f};
        gemm_k<<<gg3, 256, 0, stream>>>(jq, jk, jv);

        attn_mfma_k<<<dim3(512), 256, 0, stream>>>(Qp, Kp, Vt, ctx);

        GemmJob jo{ctx, Wto, bo, d_out, 1, 1.0f};
        gemm_k<<<gg, 256, 0, stream>>>(jo, jo, jo);
    } else {
        // ---- sequential path (40 MB) ----
        bf16* X  = (bf16*)d_ws;
        bf16* Qp = X + PE;
        bf16* Kp = Qp + PE;
        bf16* Vt = Kp + PE;
        bf16* Wtq = Vt + PE;
        bf16* Wtk = Wtq + WTE;
        bf16* Wtv = Wtk + WTE;
        bf16* Wto = Wtv + WTE;

        transpose_cvt_k<<<tg, 256, 0, stream>>>(Wq, Wk, Wv, Wo, Wtq, Wtk, Wtv, Wto);

        const dim3 cg1((unsigned)(PE / 1024), 1, 1);
        cvt_bf16_k<<<cg1, 256, 0, stream>>>(q, q, q, X, X, X);
        GemmJob jq{X, Wtq, bq, Qp, 0, qscale};
        gemm_k<<<gg, 256, 0, stream>>>(jq, jq, jq);
        cvt_bf16_k<<<cg1, 256, 0, stream>>>(k, k, k, X, X, X);
        GemmJob jk{X, Wtk, bk, Kp, 0, 1.0f};
        gemm_k<<<gg, 256, 0, stream>>>(jk, jk, jk);
        cvt_bf16_k<<<cg1, 256, 0, stream>>>(v, v, v, X, X, X);
        GemmJob jv{X, Wtv, bv, Vt, 2, 1.0f};
        gemm_k<<<gg, 256, 0, stream>>>(jv, jv, jv);

        attn_mfma_k<<<dim3(512), 256, 0, stream>>>(Qp, Kp, Vt, X);

        GemmJob jo{X, Wto, bo, d_out, 1, 1.0f};
        gemm_k<<<gg, 256, 0, stream>>>(jo, jo, jo);
    }
}

// Round 9
// 328.872 us; speedup vs baseline: 1.0471x; 1.0275x over previous
//
#include <hip/hip_runtime.h>
#include <hip/hip_bf16.h>

// MultiHeadSelfAttention  B=1, S=4096, D=1024, H=16, HD=64. fp32 I/O.
// Attention v2: 128 q-rows/block (halves K/V staging per unit work),
// coalesced global loads + swizzled ds_write (no global_load_lds gather),
// pi-permuted V so P goes register->MFMA with NO LDS round-trip.
// GEMM: R8's 128x64 + XOR swizzle (unchanged except pi-perm in mode 2).

#define S_LEN 4096
#define D_DIM 1024
#define NHEAD 16
#define HDIM  64

typedef __hip_bfloat16 bf16;
typedef __attribute__((ext_vector_type(8))) short bf16x8v;   // 16 B
typedef __attribute__((ext_vector_type(4))) float f32x4;

#define MFMA16(a, b, c) __builtin_amdgcn_mfma_f32_16x16x32_bf16((a), (b), (c), 0, 0, 0)
#define LOG2E 1.44269504088896340736f

__device__ __forceinline__ void async_cp16(const void* g, void* l) {
    __builtin_amdgcn_global_load_lds(
        (const __attribute__((address_space(1))) unsigned int*)g,
        (__attribute__((address_space(3))) unsigned int*)l, 16, 0, 0);
}

__device__ __forceinline__ short bf_bits(float x) {
    union { bf16 h; short s; } u; u.h = __float2bfloat16(x); return u.s;
}

// ---------------------------------------------------------------------------
// fp32 -> bf16 elementwise, 3 tensors via blockIdx.z.
// ---------------------------------------------------------------------------
__global__ __launch_bounds__(256) void cvt_bf16_k(
    const float* __restrict__ x0, const float* __restrict__ x1,
    const float* __restrict__ x2,
    bf16* __restrict__ y0, bf16* __restrict__ y1, bf16* __restrict__ y2)
{
    const float* x = (blockIdx.z == 0) ? x0 : (blockIdx.z == 1) ? x1 : x2;
    bf16*       y = (blockIdx.z == 0) ? y0 : (blockIdx.z == 1) ? y1 : y2;
    const size_t i = ((size_t)blockIdx.x * 256 + threadIdx.x);
    const float4 v = ((const float4*)x)[i];
    union { bf16 h[4]; short4 s; } u;
    u.h[0] = __float2bfloat16(v.x);
    u.h[1] = __float2bfloat16(v.y);
    u.h[2] = __float2bfloat16(v.z);
    u.h[3] = __float2bfloat16(v.w);
    ((short4*)y)[i] = u.s;
}

// ---------------------------------------------------------------------------
// Wt[n][k] = bf16(W[k][n]), 4 matrices via blockIdx.z.
// ---------------------------------------------------------------------------
__global__ __launch_bounds__(256) void transpose_cvt_k(
    const float* __restrict__ W0, const float* __restrict__ W1,
    const float* __restrict__ W2, const float* __restrict__ W3,
    bf16* __restrict__ T0, bf16* __restrict__ T1,
    bf16* __restrict__ T2, bf16* __restrict__ T3)
{
    const float* W = (blockIdx.z == 0) ? W0 : (blockIdx.z == 1) ? W1
                   : (blockIdx.z == 2) ? W2 : W3;
    bf16*       Wt = (blockIdx.z == 0) ? T0 : (blockIdx.z == 1) ? T1
                   : (blockIdx.z == 2) ? T2 : T3;
    __shared__ float t[32][33];
    const int bx = blockIdx.x << 5, by = blockIdx.y << 5;
    const int tx = threadIdx.x & 31, ty = threadIdx.x >> 5;
#pragma unroll
    for (int i = 0; i < 32; i += 8)
        t[ty + i][tx] = W[(size_t)(by + ty + i) * D_DIM + bx + tx];
    __syncthreads();
#pragma unroll
    for (int i = 0; i < 32; i += 8)
        Wt[(size_t)(bx + ty + i) * D_DIM + by + tx] = __float2bfloat16(t[tx][ty + i]);
}

// ---------------------------------------------------------------------------
// GEMM: C(4096x1024) = A @ Wt^T + bias, *scale. Tile 128x64, BK=64 (R8's).
// mode 0: bf16 head-major; mode 2: bf16 [h][hd][pi-permuted row]; mode 1: fp32.
// pi-perm (mode 2): within each 64-key block, key kappa is stored at position
//   s = (kappa&32) | (((kappa&15)>>2)<<3) | ((kappa&3) + 4*((kappa>>4)&1))
// so the attention kernel's PV contraction order matches its S^T register
// layout with zero data movement (see attn kernel).
// ---------------------------------------------------------------------------
struct GemmJob {
    const bf16* A; const bf16* Wt; const float* bias; void* out;
    int mode; float scale;
};

__global__ __launch_bounds__(256) void gemm_k(GemmJob j0, GemmJob j1, GemmJob j2)
{
    const GemmJob j = (blockIdx.z == 0) ? j0 : (blockIdx.z == 1) ? j1 : j2;
    const int K = D_DIM;
    const int bn = blockIdx.x << 6;
    const int bm = blockIdx.y << 7;
    const int tid = threadIdx.x;
    const int w = tid >> 6, lane = tid & 63;
    const int col = lane & 15, g = lane >> 4;
    const int wr = (w >> 1) << 6, wc = (w & 1) << 5;

    __shared__ bf16 As[128 * 64];
    __shared__ bf16 Bs[64 * 64];

    f32x4 acc[4][2];
#pragma unroll
    for (int i = 0; i < 4; ++i)
#pragma unroll
        for (int jj = 0; jj < 2; ++jj) acc[i][jj] = (f32x4){0.f, 0.f, 0.f, 0.f};

    for (int kb = 0; kb < K; kb += 64) {
        __syncthreads();
#pragma unroll
        for (int e = 0; e < 4; ++e) {
            const int lin = (e << 8) + tid;
            const int row = lin >> 3, kcs = lin & 7;
            const int kcg = kcs ^ (row & 7);
            async_cp16(j.A + (size_t)(bm + row) * K + kb + (kcg << 3), &As[lin << 3]);
        }
#pragma unroll
        for (int e = 0; e < 2; ++e) {
            const int lin = (e << 8) + tid;
            const int row = lin >> 3, kcs = lin & 7;
            const int kcg = kcs ^ (row & 7);
            async_cp16(j.Wt + (size_t)(bn + row) * K + kb + (kcg << 3), &Bs[lin << 3]);
        }
        __syncthreads();

#pragma unroll
        for (int s = 0; s < 2; ++s) {
            bf16x8v af[4], bfv[2];
#pragma unroll
            for (int i = 0; i < 4; ++i) {
                const int row = wr + (i << 4) + col;
                af[i] = *(const bf16x8v*)&As[((row << 3) + (((s << 2) + g) ^ (row & 7))) << 3];
            }
#pragma unroll
            for (int jj = 0; jj < 2; ++jj) {
                const int row = wc + (jj << 4) + col;
                bfv[jj] = *(const bf16x8v*)&Bs[((row << 3) + (((s << 2) + g) ^ (row & 7))) << 3];
            }
#pragma unroll
            for (int i = 0; i < 4; ++i)
#pragma unroll
                for (int jj = 0; jj < 2; ++jj)
                    acc[i][jj] = MFMA16(af[i], bfv[jj], acc[i][jj]);
        }
    }

#pragma unroll
    for (int i = 0; i < 4; ++i)
#pragma unroll
    for (int jj = 0; jj < 2; ++jj)
#pragma unroll
    for (int reg = 0; reg < 4; ++reg) {
        const int row = bm + wr + (i << 4) + (g << 2) + reg;  // C/D: row=(lane>>4)*4+reg
        const int cg  = bn + wc + (jj << 4) + col;            // C/D: col=lane&15
        const float vv = (acc[i][jj][reg] + j.bias[cg]) * j.scale;
        if (j.mode == 0)
            ((bf16*)j.out)[(((size_t)(cg >> 6)) * S_LEN + row) * HDIM + (cg & 63)] =
                __float2bfloat16(vv);
        else if (j.mode == 2) {
            const int lr = row & 63;
            const int prow = (row & ~63) | (lr & 32)
                           | (((lr & 15) >> 2) << 3)
                           | ((lr & 3) + (((lr >> 4) & 1) << 2));
            ((bf16*)j.out)[((size_t)(cg >> 6) * HDIM + (cg & 63)) * S_LEN + prow] =
                __float2bfloat16(vv);
        } else
            ((float*)j.out)[(size_t)row * D_DIM + cg] = vv;
    }
}

// ---------------------------------------------------------------------------
// Flash attention v2. Block = 128 q-rows (4 waves x 32, 2 m-subtiles/wave).
// Grid 512 (32 q-blocks x 16 heads), heavy-first. nkb = 2*qb+2 K-tiles.
//
// Staging: COALESCED global loads of tile kb+1 into regs during compute of kb,
// then swizzled ds_write_b128 -> single 16 KB LDS buffer, 2 barriers/tile.
// LDS slot for granule (key-or-dim row r = 16t+c, 8-elem chunk G):
//   slot = t*128 + G*16 + (c^G)
//   write banks: quarter-wave covers (c in {0,1}) x (G 0..7): start bank
//     4*(c^G) hits {0,4,..,28} twice -> 2-way = free (m136).
//   frag-read (t, Gr): lanes col read slot base + (col^Gr): start banks
//     4*perm(col) -> {0,4,..,28} x2 -> 2-way = free.
//
// pi-trick: S^T lane (g,col) holds p for keys {16t+4g+reg}, q=col. PV's
// A-operand at lane (g,col) needs P[q=col][k-chunk g*8..], k in ANY fixed
// order shared with V. Choose pi(8g+j) = 4g+j (j<4), 16+4g+(j-4) (j>=4),
// +32 analog -> pf0 = pack(p[t0],p[t1]), pf1 = pack(p[t2],p[t3]): zero
// cross-lane movement. V arrives pi-permuted from the GEMM epilogue.
// ---------------------------------------------------------------------------
__global__ __launch_bounds__(256) void attn_mfma_k(
    const bf16* __restrict__ Qp, const bf16* __restrict__ Kp,
    const bf16* __restrict__ Vtm, bf16* __restrict__ ctx)
{
    __shared__ bf16 Ks[4096];    // 8 KB
    __shared__ bf16 Vs[4096];    // 8 KB

    const int bid = blockIdx.x;
    const int qb  = 31 - (bid >> 4);        // heavy-first
    const int h   = bid & 15;
    const int q0  = qb << 7;                // 128 q-rows
    const int nkb = (qb << 1) + 2;
    const int tid = threadIdx.x, w = tid >> 6, lane = tid & 63;
    const int col = lane & 15, g = lane >> 4;

    const bf16* Kh = Kp  + (size_t)h * S_LEN * HDIM;
    const bf16* Vh = Vtm + (size_t)h * HDIM * S_LEN;

    // Q B-frags for the wave's 2 m-subtiles (u): rows q0 + w*32 + u*16 + col
    bf16x8v qf[2][2];
#pragma unroll
    for (int u = 0; u < 2; ++u) {
        const size_t qrb = ((size_t)h * S_LEN + q0 + (w << 5) + (u << 4) + col) * HDIM + (g << 3);
        qf[u][0] = *(const bf16x8v*)(Qp + qrb);
        qf[u][1] = *(const bf16x8v*)(Qp + qrb + 32);
    }

    // granule ids and LDS slots (kb-invariant)
    const int L0 = tid, L1 = 256 + tid;
    const int k0r = L0 >> 3, k0G = L0 & 7;
    const int k1r = L1 >> 3, k1G = L1 & 7;
    const int sl0 = ((k0r >> 4) << 7) + (k0G << 4) + ((k0r & 15) ^ k0G);
    const int sl1 = ((k1r >> 4) << 7) + (k1G << 4) + ((k1r & 15) ^ k1G);
    const size_t v0base = (size_t)k0r * S_LEN + (k0G << 3);
    const size_t v1base = (size_t)k1r * S_LEN + (k1G << 3);

    float pl[2] = {0.f, 0.f};
    f32x4 acco[2][4];
#pragma unroll
    for (int u = 0; u < 2; ++u)
#pragma unroll
        for (int t = 0; t < 4; ++t) acco[u][t] = (f32x4){0.f, 0.f, 0.f, 0.f};

    // prologue: tile 0 (K tile is one contiguous 8 KB stream)
    {
        bf16x8v ka = *(const bf16x8v*)(Kh + ((size_t)L0 << 3));
        bf16x8v kb_ = *(const bf16x8v*)(Kh + ((size_t)L1 << 3));
        bf16x8v va = *(const bf16x8v*)(Vh + v0base);
        bf16x8v vb = *(const bf16x8v*)(Vh + v1base);
        *(bf16x8v*)&Ks[sl0 << 3] = ka;
        *(bf16x8v*)&Ks[sl1 << 3] = kb_;
        *(bf16x8v*)&Vs[sl0 << 3] = va;
        *(bf16x8v*)&Vs[sl1 << 3] = vb;
    }
    __syncthreads();

    for (int kb = 0; kb < nkb; ++kb) {
        // issue coalesced loads for tile kb+1 (consumed after the barrier)
        bf16x8v kn0, kn1, vn0, vn1;
        const bool more = (kb + 1 < nkb);
        if (more) {
            const size_t kbase = (size_t)(kb + 1) << 12;   // *4096 elems
            kn0 = *(const bf16x8v*)(Kh + kbase + ((size_t)L0 << 3));
            kn1 = *(const bf16x8v*)(Kh + kbase + ((size_t)L1 << 3));
            const int koff = (kb + 1) << 6;
            vn0 = *(const bf16x8v*)(Vh + v0base + koff);
            vn1 = *(const bf16x8v*)(Vh + v1base + koff);
        }

        // S^T = MFMA(K, Q): kf shared by both m-subtiles
        f32x4 sa[2][4];
#pragma unroll
        for (int u = 0; u < 2; ++u)
#pragma unroll
            for (int t = 0; t < 4; ++t) sa[u][t] = (f32x4){0.f, 0.f, 0.f, 0.f};
#pragma unroll
        for (int t = 0; t < 4; ++t) {
            const int G0 = g, G1 = 4 + g;
            const bf16x8v kf0 = *(const bf16x8v*)&Ks[(((t << 7) + (G0 << 4) + (col ^ G0))) << 3];
            const bf16x8v kf1 = *(const bf16x8v*)&Ks[(((t << 7) + (G1 << 4) + (col ^ G1))) << 3];
            sa[0][t] = MFMA16(kf0, qf[0][0], sa[0][t]);
            sa[0][t] = MFMA16(kf1, qf[0][1], sa[0][t]);
            sa[1][t] = MFMA16(kf0, qf[1][0], sa[1][t]);
            sa[1][t] = MFMA16(kf1, qf[1][1], sa[1][t]);
        }

        // exp2 softmax (zero-shift exact) + pi-pack into PV A-frags
        bf16x8v pf[2][2];
        const bool maskzone = (kb + 2 >= nkb);
#pragma unroll
        for (int u = 0; u < 2; ++u) {
            float ps[4][4];
            if (!maskzone) {
#pragma unroll
                for (int t = 0; t < 4; ++t)
#pragma unroll
                    for (int reg = 0; reg < 4; ++reg)
                        ps[t][reg] = __builtin_amdgcn_exp2f(sa[u][t][reg]);
            } else {
                const int qrel = q0 + (w << 5) + (u << 4) + col - (kb << 6);
#pragma unroll
                for (int t = 0; t < 4; ++t)
#pragma unroll
                    for (int reg = 0; reg < 4; ++reg) {
                        const int krel = (t << 4) + (g << 2) + reg;
                        ps[t][reg] = (krel > qrel) ? 0.f
                                   : __builtin_amdgcn_exp2f(sa[u][t][reg]);
                    }
            }
#pragma unroll
            for (int t = 0; t < 4; ++t)
                pl[u] += (ps[t][0] + ps[t][1]) + (ps[t][2] + ps[t][3]);
            bf16x8v a, b;
#pragma unroll
            for (int reg = 0; reg < 4; ++reg) {
                a[reg]     = bf_bits(ps[0][reg]);
                a[4 + reg] = bf_bits(ps[1][reg]);
                b[reg]     = bf_bits(ps[2][reg]);
                b[4 + reg] = bf_bits(ps[3][reg]);
            }
            pf[u][0] = a; pf[u][1] = b;
        }

        // O += P V (V is pi-permuted in memory; vf shared by both subtiles)
#pragma unroll
        for (int t = 0; t < 4; ++t) {
            const int G0 = g, G1 = 4 + g;
            const bf16x8v vf0 = *(const bf16x8v*)&Vs[(((t << 7) + (G0 << 4) + (col ^ G0))) << 3];
            const bf16x8v vf1 = *(const bf16x8v*)&Vs[(((t << 7) + (G1 << 4) + (col ^ G1))) << 3];
            acco[0][t] = MFMA16(pf[0][0], vf0, acco[0][t]);
            acco[0][t] = MFMA16(pf[0][1], vf1, acco[0][t]);
            acco[1][t] = MFMA16(pf[1][0], vf0, acco[1][t]);
            acco[1][t] = MFMA16(pf[1][1], vf1, acco[1][t]);
        }

        if (more) {
            __syncthreads();                 // everyone done reading tile kb
            *(bf16x8v*)&Ks[sl0 << 3] = kn0;  // waits vmcnt for the loads
            *(bf16x8v*)&Ks[sl1 << 3] = kn1;
            *(bf16x8v*)&Vs[sl0 << 3] = vn0;
            *(bf16x8v*)&Vs[sl1 << 3] = vn1;
            __syncthreads();                 // tile kb+1 visible
        }
    }

    // l(q=col) per subtile: reduce over g-lanes, redistribute to q=4g+reg
#pragma unroll
    for (int u = 0; u < 2; ++u) {
        float l = pl[u];
        l += __shfl_xor(l, 16);
        l += __shfl_xor(l, 32);
#pragma unroll
        for (int reg = 0; reg < 4; ++reg) {
            const float lr = __shfl(l, (g << 2) + reg);
#pragma unroll
            for (int t = 0; t < 4; ++t) {
                const int row = q0 + (w << 5) + (u << 4) + (g << 2) + reg;
                ctx[(size_t)row * D_DIM + h * HDIM + (t << 4) + col] =
                    __float2bfloat16(acco[u][t][reg] / lr);
            }
        }
    }
}

// ---------------------------------------------------------------------------
extern "C" void kernel_launch(void* const* d_in, const int* in_sizes, int n_in,
                              void* d_out, int out_size, void* d_ws, size_t ws_size,
                              hipStream_t stream)
{
    const float* q  = (const float*)d_in[0];
    const float* k  = (const float*)d_in[1];
    const float* v  = (const float*)d_in[2];
    // d_in[3] = causal mask, implemented analytically
    const float* Wq = (const float*)d_in[4];
    const float* bq = (const float*)d_in[5];
    const float* Wk = (const float*)d_in[6];
    const float* bk = (const float*)d_in[7];
    const float* Wv = (const float*)d_in[8];
    const float* bv = (const float*)d_in[9];
    const float* Wo = (const float*)d_in[10];
    const float* bo = (const float*)d_in[11];

    const size_t PE  = (size_t)S_LEN * D_DIM;
    const size_t WTE = (size_t)D_DIM * D_DIM;
    const float qscale = 0.125f * LOG2E;   // fold 1/sqrt(64) + log2(e) into Qp

    const dim3 tg(32, 32, 4);
    const dim3 gg(D_DIM / 64, S_LEN / 128, 1);
    const dim3 gg3(D_DIM / 64, S_LEN / 128, 3);
    const dim3 cg((unsigned)(PE / 1024), 1, 3);

    if (ws_size >= (size_t)64 * 1024 * 1024) {
        // ---- fused-QKV path (56 MB) ----
        bf16* Qb = (bf16*)d_ws;
        bf16* Kb = Qb + PE;
        bf16* Vb = Kb + PE;
        bf16* Qp = Vb + PE;
        bf16* Kp = Qp + PE;
        bf16* Vt = Kp + PE;
        bf16* Wtq = Vt + PE;
        bf16* Wtk = Wtq + WTE;
        bf16* Wtv = Wtk + WTE;
        bf16* Wto = Wtv + WTE;
        bf16* ctx = Qb;

        transpose_cvt_k<<<tg, 256, 0, stream>>>(Wq, Wk, Wv, Wo, Wtq, Wtk, Wtv, Wto);
        cvt_bf16_k<<<cg, 256, 0, stream>>>(q, k, v, Qb, Kb, Vb);

        GemmJob jq{Qb, Wtq, bq, Qp, 0, qscale};
        GemmJob jk{Kb, Wtk, bk, Kp, 0, 1.0f};
        GemmJob jv{Vb, Wtv, bv, Vt, 2, 1.0f};
        gemm_k<<<gg3, 256, 0, stream>>>(jq, jk, jv);

        attn_mfma_k<<<dim3(512), 256, 0, stream>>>(Qp, Kp, Vt, ctx);

        GemmJob jo{ctx, Wto, bo, d_out, 1, 1.0f};
        gemm_k<<<gg, 256, 0, stream>>>(jo, jo, jo);
    } else {
        // ---- sequential path (40 MB) ----
        bf16* X  = (bf16*)d_ws;
        bf16* Qp = X + PE;
        bf16* Kp = Qp + PE;
        bf16* Vt = Kp + PE;
        bf16* Wtq = Vt + PE;
        bf16* Wtk = Wtq + WTE;
        bf16* Wtv = Wtk + WTE;
        bf16* Wto = Wtv + WTE;

        transpose_cvt_k<<<tg, 256, 0, stream>>>(Wq, Wk, Wv, Wo, Wtq, Wtk, Wtv, Wto);

        const dim3 cg1((unsigned)(PE / 1024), 1, 1);
        cvt_bf16_k<<<cg1, 256, 0, stream>>>(q, q, q, X, X, X);
        GemmJob jq{X, Wtq, bq, Qp, 0, qscale};
        gemm_k<<<gg, 256, 0, stream>>>(jq, jq, jq);
        cvt_bf16_k<<<cg1, 256, 0, stream>>>(k, k, k, X, X, X);
        GemmJob jk{X, Wtk, bk, Kp, 0, 1.0f};
        gemm_k<<<gg, 256, 0, stream>>>(jk, jk, jk);
        cvt_bf16_k<<<cg1, 256, 0, stream>>>(v, v, v, X, X, X);
        GemmJob jv{X, Wtv, bv, Vt, 2, 1.0f};
        gemm_k<<<gg, 256, 0, stream>>>(jv, jv, jv);

        attn_mfma_k<<<dim3(512), 256, 0, stream>>>(Qp, Kp, Vt, X);

        GemmJob jo{X, Wto, bo, d_out, 1, 1.0f};
        gemm_k<<<gg, 256, 0, stream>>>(jo, jo, jo);
    }
}